// Round 9
// baseline (703.359 us; speedup 1.0000x reference)
//
#include <hip/hip_runtime.h>

__device__ __forceinline__ float lrelu(float v){ return v > 0.f ? v : 0.01f*v; }

typedef __attribute__((ext_vector_type(8))) short v8s;   // 8 bf16 (4 VGPRs)
typedef __attribute__((ext_vector_type(4))) float v4f;   // MFMA acc

// bf16 helpers (RNE pack; unpack via shift)
__device__ __forceinline__ unsigned short f2bf(float f){
    union{float f; unsigned int i;} v; v.f = f;
    unsigned int u = v.i;
    return (unsigned short)((u + 0x7fffu + ((u >> 16) & 1u)) >> 16);
}
__device__ __forceinline__ unsigned int pack2(float a, float b){
    return (unsigned int)f2bf(a) | ((unsigned int)f2bf(b) << 16);
}
__device__ __forceinline__ float bflo(unsigned int u){
    union{unsigned int i; float f;} v; v.i = u << 16; return v.f;
}
__device__ __forceinline__ float bfhi(unsigned int u){
    union{unsigned int i; float f;} v; v.i = u & 0xffff0000u; return v.f;
}
__device__ __forceinline__ float bf2f(unsigned short s){
    union{unsigned int i; float f;} v; v.i = ((unsigned int)s) << 16; return v.f;
}

// ================= CSR build =================================================
__global__ __launch_bounds__(256) void k_hist(
    const int* __restrict__ ei, int* __restrict__ deg, int E)
{
    int e = blockIdx.x * 256 + threadIdx.x;
    if (e >= E) return;
    atomicAdd(&deg[ei[E + e]], 1);
}

__global__ __launch_bounds__(256) void k_scan1(
    const int* __restrict__ deg, int* __restrict__ rowptr,
    int* __restrict__ bsum, int N)
{
    __shared__ int sh[256];
    int t = threadIdx.x;
    int i = blockIdx.x * 256 + t;
    int v = (i < N) ? deg[i] : 0;
    sh[t] = v;
    __syncthreads();
    #pragma unroll
    for (int off = 1; off < 256; off <<= 1) {
        int add = (t >= off) ? sh[t - off] : 0;
        __syncthreads();
        sh[t] += add;
        __syncthreads();
    }
    if (i < N) rowptr[i] = sh[t] - v;
    if (t == 255) bsum[blockIdx.x] = sh[t];
}

__global__ __launch_bounds__(512) void k_scan2(int* __restrict__ bsum, int nb)
{
    __shared__ int sh[512];
    int t = threadIdx.x;
    int v = (t < nb) ? bsum[t] : 0;
    sh[t] = v;
    __syncthreads();
    #pragma unroll
    for (int off = 1; off < 512; off <<= 1) {
        int add = (t >= off) ? sh[t - off] : 0;
        __syncthreads();
        sh[t] += add;
        __syncthreads();
    }
    if (t < nb) bsum[t] = sh[t] - v;
}

__global__ __launch_bounds__(256) void k_scan3(
    int* __restrict__ rowptr, int* __restrict__ cursor,
    const int* __restrict__ bsum, int N)
{
    int i = blockIdx.x * 256 + threadIdx.x;
    if (i >= N) return;
    int rp = rowptr[i] + bsum[i >> 8];
    rowptr[i] = rp;
    cursor[i] = rp;
}

// bucket cursors: bucket b = dst>>8; start slot = rowptr[b<<8]
__global__ __launch_bounds__(512) void k_binit(
    const int* __restrict__ rowptr, int* __restrict__ bcur, int N)
{
    int b = threadIdx.x;
    int node = b << 8;
    if (node < N) bcur[b] = rowptr[node];
}

// cast x -> bf16 (8 floats / thread)
__global__ __launch_bounds__(256) void k_castx(
    const float* __restrict__ x, unsigned int* __restrict__ xb, int M8)
{
    int i = blockIdx.x * 256 + threadIdx.x;
    if (i >= M8) return;
    const float4* p = reinterpret_cast<const float4*>(x) + (size_t)i * 2;
    float4 a = p[0], b = p[1];
    uint4 o;
    o.x = pack2(a.x, a.y); o.y = pack2(a.z, a.w);
    o.z = pack2(b.x, b.y); o.w = pack2(b.z, b.w);
    reinterpret_cast<uint4*>(xb)[i] = o;
}

// one-time transpose+cast of weights to bf16 [N][K] layouts.
__global__ __launch_bounds__(256) void k_castw(
    const float* __restrict__ W2a, const float* __restrict__ W2b,
    const float* __restrict__ We1, const float* __restrict__ We2,
    unsigned short* __restrict__ W2aT, unsigned short* __restrict__ W2bT,
    unsigned short* __restrict__ WeT1, unsigned short* __restrict__ WeT2)
{
    int i = blockIdx.x * 256 + threadIdx.x;
    if (i < 128 * 64) {
        int n = i >> 6, k = i & 63;
        W2aT[i] = f2bf(W2a[k * 128 + n]);
    }
    int j = i - 128 * 64;
    if (j >= 0 && j < 256 * 128) {
        int n = j >> 7, k = j & 127;
        W2bT[j] = f2bf(W2b[k * 256 + n]);
    }
    int q1 = i - (128 * 64 + 256 * 128);
    if (q1 >= 0 && q1 < 32 * 32) {
        int cch = q1 >> 5, k = q1 & 31;
        WeT1[q1] = (k < 16) ? f2bf(We1[k * 32 + cch]) : (unsigned short)0;
    }
    int q2 = q1 - 32 * 32;
    if (q2 >= 0 && q2 < 64 * 32) {
        int cch = q2 >> 5, k = q2 & 31;
        WeT2[q2] = (k < 16) ? f2bf(We2[k * 64 + cch]) : (unsigned short)0;
    }
}

// ---- pass 1: block-local LDS bucketing; burst writes into reserved ranges ---
// Bucket b = dst>>8 (<=512 buckets). Staging index space == CSR slot space
// (bucket start = rowptr[b<<8]), unordered within bucket.
#define BCH 4096
__global__ __launch_bounds__(256) void k_bucket(
    const int* __restrict__ ei, const float* __restrict__ ea,
    int* __restrict__ bcur, int2* __restrict__ sA, uint4* __restrict__ sB,
    int E)
{
    __shared__ int hist[512];
    __shared__ int base[512];
    __shared__ int lcur[512];
    const int tid = threadIdx.x;
    const int c0 = blockIdx.x * BCH;
    int cend = c0 + BCH; if (cend > E) cend = E;
    hist[tid] = 0; hist[tid + 256] = 0;
    __syncthreads();
    for (int e = c0 + tid; e < cend; e += 256)
        atomicAdd(&hist[ei[E + e] >> 8], 1);
    __syncthreads();
    {
        int h0 = hist[tid], h1 = hist[tid + 256];
        base[tid]       = h0 ? atomicAdd(&bcur[tid], h0) : 0;
        base[tid + 256] = h1 ? atomicAdd(&bcur[tid + 256], h1) : 0;
        lcur[tid] = 0; lcur[tid + 256] = 0;
    }
    __syncthreads();
    for (int e = c0 + tid; e < cend; e += 256) {
        int d = ei[E + e];
        int b = d >> 8;
        int pos = base[b] + atomicAdd(&lcur[b], 1);
        int s = ei[e];
        const float4* p = reinterpret_cast<const float4*>(ea) + (size_t)e * 4;
        float4 a = p[0], bb = p[1], cc = p[2], f = p[3];
        uint4 o0, o1;
        o0.x = pack2(a.x, a.y);   o0.y = pack2(a.z, a.w);
        o0.z = pack2(bb.x, bb.y); o0.w = pack2(bb.z, bb.w);
        o1.x = pack2(cc.x, cc.y); o1.y = pack2(cc.z, cc.w);
        o1.z = pack2(f.x, f.y);   o1.w = pack2(f.z, f.w);
        sB[(size_t)pos * 2]     = o0;
        sB[(size_t)pos * 2 + 1] = o1;
        int2 rr; rr.x = s; rr.y = d;
        sA[pos] = rr;
    }
}

// ---- pass 2: one block per bucket; exclusive slot region -> L2-merged writes
__global__ __launch_bounds__(256) void k_order(
    const int2* __restrict__ sA, const uint4* __restrict__ sB,
    const int* __restrict__ rowptr, int* __restrict__ cursor,
    int2* __restrict__ csr2, uint4* __restrict__ eab, int E, int NBK)
{
    int b = blockIdx.x;
    int s0 = rowptr[b << 8];
    int e0 = (b + 1 < NBK) ? rowptr[(b + 1) << 8] : E;
    for (int i = s0 + threadIdx.x; i < e0; i += 256) {
        int2 r = sA[i];
        int slot = atomicAdd(&cursor[r.y], 1);
        csr2[slot] = r;
        eab[(size_t)slot * 2]     = sB[(size_t)i * 2];
        eab[(size_t)slot * 2 + 1] = sB[(size_t)i * 2 + 1];
    }
}

#define AGG_SPW 64

// ============ conv2 aggregation: MFMA edge-MLP + transposed accumulate =======
__global__ __launch_bounds__(256) void k_agg2(
    const unsigned short* __restrict__ xb,   // h1b [N][64] bf16
    const uint4* __restrict__ eab,
    const unsigned short* __restrict__ WeT,  // [64][32] bf16, K-padded
    const float* __restrict__ be,
    const int2* __restrict__ csr2, float* __restrict__ agg, int E)
{
    __shared__ __align__(16) float lds[4][2][16][68];
    const int tid  = threadIdx.x;
    const int wv   = tid >> 6;
    const int lane = tid & 63;
    const int lid  = lane & 15;
    const int quad = lane >> 4;
    const int wave = __builtin_amdgcn_readfirstlane((blockIdx.x * 256 + tid) >> 6);
    const int s0 = wave * AGG_SPW;
    if (s0 >= E) return;
    const int nsl = (s0 + AGG_SPW <= E) ? AGG_SPW : E - s0;

    v8s af0 = *reinterpret_cast<const v8s*>(WeT + lid * 32 + quad * 8);
    v8s af1 = *reinterpret_cast<const v8s*>(WeT + (16 + lid) * 32 + quad * 8);
    v8s af2 = *reinterpret_cast<const v8s*>(WeT + (32 + lid) * 32 + quad * 8);
    v8s af3 = *reinterpret_cast<const v8s*>(WeT + (48 + lid) * 32 + quad * 8);
    const float biasc = be[lane];
    const int2*  cp = csr2 + s0;
    const uint4* ep = eab + (size_t)s0 * 2;

    unsigned short xv[2][16];
    int dsv[2][16];
    float acc = 0.f;
    int   cur = cp[0].y;
    bool  owned = false;

    auto GATHER = [&](int t) {
        const int base = t * 16;
        const int cnt = nsl - base;
        #pragma unroll
        for (int e = 0; e < 16; ++e) {
            int ee = (e < cnt) ? e : cnt - 1;
            int2 r = cp[base + ee];
            dsv[t & 1][e] = r.y;
            xv[t & 1][e] = xb[(unsigned)r.x * 64u + (unsigned)lane];
        }
    };
    auto MFMA = [&](int t) {
        int sl = t * 16 + lid;
        if (sl > nsl - 1) sl = nsl - 1;
        uint4 bw = {0u, 0u, 0u, 0u};
        if (quad < 2) bw = ep[2 * sl + quad];
        union { uint4 u; v8s s; } uu; uu.u = bw;
        v8s bf = uu.s;
        v4f d0 = {0.f, 0.f, 0.f, 0.f}, d1 = d0, d2 = d0, d3 = d0;
        d0 = __builtin_amdgcn_mfma_f32_16x16x32_bf16(af0, bf, d0, 0, 0, 0);
        d1 = __builtin_amdgcn_mfma_f32_16x16x32_bf16(af1, bf, d1, 0, 0, 0);
        d2 = __builtin_amdgcn_mfma_f32_16x16x32_bf16(af2, bf, d2, 0, 0, 0);
        d3 = __builtin_amdgcn_mfma_f32_16x16x32_bf16(af3, bf, d3, 0, 0, 0);
        float* lp = &lds[wv][t & 1][lid][quad * 4];
        *reinterpret_cast<v4f*>(lp)      = d0;
        *reinterpret_cast<v4f*>(lp + 16) = d1;
        *reinterpret_cast<v4f*>(lp + 32) = d2;
        *reinterpret_cast<v4f*>(lp + 48) = d3;
    };
    auto ACCUM = [&](int t) {
        const int cnt = nsl - t * 16;
        #pragma unroll
        for (int e = 0; e < 16; ++e) {
            if (e < cnt) {
                float ls = lds[wv][t & 1][e][lane];
                float m = ls + biasc + bf2f(xv[t & 1][e]);
                m = m > 0.f ? m : 0.f;
                int d = dsv[t & 1][e];
                if (d != cur) {
                    if (owned) agg[(unsigned)cur * 64u + lane] = acc;
                    else       atomicAdd(&agg[(unsigned)cur * 64u + lane], acc);
                    acc = 0.f; cur = d; owned = true;
                }
                acc += m;
            }
        }
    };

    GATHER(0); MFMA(0);
    #pragma unroll
    for (int t = 0; t < 4; ++t) {
        if (t * 16 < nsl) {
            if ((t + 1) < 4 && (t + 1) * 16 < nsl) { GATHER(t + 1); MFMA(t + 1); }
            ACCUM(t);
        }
    }
    atomicAdd(&agg[(unsigned)cur * 64u + lane], acc);
}

// ============ conv1 aggregation: same structure, C=32, 2 edges/iter ==========
__global__ __launch_bounds__(256) void k_agg1(
    const unsigned short* __restrict__ xb,   // [N][32] bf16
    const uint4* __restrict__ eab,
    const unsigned short* __restrict__ WeT,  // [32][32] bf16, K-padded
    const float* __restrict__ be,
    const int2* __restrict__ csr2, float* __restrict__ agg, int E)
{
    __shared__ __align__(16) float lds[4][2][16][36];
    const int tid  = threadIdx.x;
    const int wv   = tid >> 6;
    const int lane = tid & 63;
    const int lid  = lane & 15;
    const int quad = lane >> 4;
    const int c    = lane & 31;
    const int sub  = lane >> 5;
    const int wave = __builtin_amdgcn_readfirstlane((blockIdx.x * 256 + tid) >> 6);
    const int s0 = wave * AGG_SPW;
    if (s0 >= E) return;
    const int nsl = (s0 + AGG_SPW <= E) ? AGG_SPW : E - s0;

    v8s af0 = *reinterpret_cast<const v8s*>(WeT + lid * 32 + quad * 8);
    v8s af1 = *reinterpret_cast<const v8s*>(WeT + (16 + lid) * 32 + quad * 8);
    const float biasc = be[c];
    const int2*  cp = csr2 + s0;
    const uint4* ep = eab + (size_t)s0 * 2;

    unsigned short xv[2][8];
    int dsv[2][8];
    float acc = 0.f;
    int cur = cp[(sub < nsl) ? sub : 0].y;

    auto GATHER = [&](int t) {
        #pragma unroll
        for (int i = 0; i < 8; ++i) {
            int e = t * 16 + 2 * i + sub;
            int ee = (e < nsl) ? e : nsl - 1;
            int2 r = cp[ee];
            dsv[t & 1][i] = r.y;
            xv[t & 1][i] = xb[(unsigned)r.x * 32u + (unsigned)c];
        }
    };
    auto MFMA = [&](int t) {
        int sl = t * 16 + lid;
        if (sl > nsl - 1) sl = nsl - 1;
        uint4 bw = {0u, 0u, 0u, 0u};
        if (quad < 2) bw = ep[2 * sl + quad];
        union { uint4 u; v8s s; } uu; uu.u = bw;
        v8s bf = uu.s;
        v4f d0 = {0.f, 0.f, 0.f, 0.f}, d1 = d0;
        d0 = __builtin_amdgcn_mfma_f32_16x16x32_bf16(af0, bf, d0, 0, 0, 0);
        d1 = __builtin_amdgcn_mfma_f32_16x16x32_bf16(af1, bf, d1, 0, 0, 0);
        float* lp = &lds[wv][t & 1][lid][quad * 4];
        *reinterpret_cast<v4f*>(lp)      = d0;
        *reinterpret_cast<v4f*>(lp + 16) = d1;
    };
    auto ACCUM = [&](int t) {
        #pragma unroll
        for (int i = 0; i < 8; ++i) {
            int e = t * 16 + 2 * i + sub;
            if (e < nsl) {
                float ls = lds[wv][t & 1][2 * i + sub][c];
                float m = ls + biasc + bf2f(xv[t & 1][i]);
                m = m > 0.f ? m : 0.f;
                int d = dsv[t & 1][i];
                if (d != cur) {
                    atomicAdd(&agg[(unsigned)cur * 32u + c], acc);
                    acc = 0.f; cur = d;
                }
                acc += m;
            }
        }
    };

    GATHER(0); MFMA(0);
    #pragma unroll
    for (int t = 0; t < 4; ++t) {
        if (t * 16 < nsl) {
            if ((t + 1) < 4 && (t + 1) * 16 < nsl) { GATHER(t + 1); MFMA(t + 1); }
            ACCUM(t);
        }
    }
    atomicAdd(&agg[(unsigned)cur * 32u + c], acc);
}

// ============ conv1 node nn, fused; writes h1b bf16 only =====================
__global__ __launch_bounds__(256, 4) void k_mlp1(
    const float* __restrict__ x, const float* __restrict__ agg1,
    const float* __restrict__ W1a, const float* __restrict__ b1a,
    const float* __restrict__ W1b, const float* __restrict__ b1b,
    unsigned int* __restrict__ h1b, int N)
{
    __shared__ float ts[64][33];
    const int tid = threadIdx.x;
    const int n0 = blockIdx.x * 64;
    const int row = tid & 63;
    const int grp = __builtin_amdgcn_readfirstlane(tid >> 6);
    const int g = n0 + row;

    float hv[32];
    if (g < N) {
        const float4* xp = reinterpret_cast<const float4*>(x) + (size_t)g * 8;
        const float4* ap = reinterpret_cast<const float4*>(agg1) + (size_t)g * 8;
        #pragma unroll
        for (int q = 0; q < 8; ++q) {
            float4 a = xp[q], b = ap[q];
            hv[4*q+0]=a.x+b.x; hv[4*q+1]=a.y+b.y;
            hv[4*q+2]=a.z+b.z; hv[4*q+3]=a.w+b.w;
        }
    } else {
        #pragma unroll
        for (int q = 0; q < 32; ++q) hv[q] = 0.f;
    }

    {
        const int c0 = grp * 8;
        float acc[8];
        #pragma unroll
        for (int i = 0; i < 8; ++i) acc[i] = b1a[c0 + i];
        for (int k = 0; k < 32; ++k) {
            float h = hv[k];
            const float* w = W1a + k*32 + c0;
            #pragma unroll
            for (int i = 0; i < 8; ++i) acc[i] = fmaf(h, w[i], acc[i]);
        }
        #pragma unroll
        for (int i = 0; i < 8; ++i) ts[row][c0 + i] = lrelu(acc[i]);
    }
    __syncthreads();

    {
        const int c0 = grp * 16;
        float acc[16];
        #pragma unroll
        for (int i = 0; i < 16; ++i) acc[i] = b1b[c0 + i];
        for (int k = 0; k < 32; ++k) {
            float tv = ts[row][k];
            const float* w = W1b + k*64 + c0;
            #pragma unroll
            for (int i = 0; i < 16; ++i) acc[i] = fmaf(tv, w[i], acc[i]);
        }
        if (g < N) {
            #pragma unroll
            for (int i = 0; i < 16; ++i) acc[i] = lrelu(acc[i]);
            uint4 p0, p1;
            p0.x = pack2(acc[0],  acc[1]);  p0.y = pack2(acc[2],  acc[3]);
            p0.z = pack2(acc[4],  acc[5]);  p0.w = pack2(acc[6],  acc[7]);
            p1.x = pack2(acc[8],  acc[9]);  p1.y = pack2(acc[10], acc[11]);
            p1.z = pack2(acc[12], acc[13]); p1.w = pack2(acc[14], acc[15]);
            uint4* bp = reinterpret_cast<uint4*>(h1b + (size_t)g*32 + (c0>>1));
            bp[0] = p0; bp[1] = p1;
        }
    }
}

// ============ conv2 node nn via MFMA bf16 (stages from h1b bf16) =============
__global__ __launch_bounds__(256) void k_mlp2(
    const unsigned int* __restrict__ h1b, const float* __restrict__ agg2,
    const unsigned short* __restrict__ W2aT, const float* __restrict__ b2a,
    const unsigned short* __restrict__ W2bT, const float* __restrict__ b2b,
    unsigned short* __restrict__ h2b, int N)
{
    __shared__ unsigned short hs[64][72];    // 64 x 64 bf16 (+pad)
    __shared__ unsigned short ts[64][136];   // 64 x 128 bf16 (+pad)
    const int tid = threadIdx.x;
    const int n0 = blockIdx.x * 64;

    // stage hs = bf16(h1 + agg2)
    {
        int r = tid >> 2, cseg = (tid & 3) * 16;
        int g = n0 + r;
        uint4 o0 = {0,0,0,0}, o1 = {0,0,0,0};
        if (g < N) {
            const uint4* hp = reinterpret_cast<const uint4*>(
                                  h1b + (size_t)g*32 + (cseg>>1));
            const float4* ap = reinterpret_cast<const float4*>(agg2)
                               + (size_t)g*16 + (cseg>>2);
            uint4 u0 = hp[0], u1 = hp[1];
            float4 b0=ap[0], b1=ap[1], b2=ap[2], b3=ap[3];
            o0.x = pack2(bflo(u0.x)+b0.x, bfhi(u0.x)+b0.y);
            o0.y = pack2(bflo(u0.y)+b0.z, bfhi(u0.y)+b0.w);
            o0.z = pack2(bflo(u0.z)+b1.x, bfhi(u0.z)+b1.y);
            o0.w = pack2(bflo(u0.w)+b1.z, bfhi(u0.w)+b1.w);
            o1.x = pack2(bflo(u1.x)+b2.x, bfhi(u1.x)+b2.y);
            o1.y = pack2(bflo(u1.y)+b2.z, bfhi(u1.y)+b2.w);
            o1.z = pack2(bflo(u1.z)+b3.x, bfhi(u1.z)+b3.y);
            o1.w = pack2(bflo(u1.w)+b3.z, bfhi(u1.w)+b3.w);
        }
        uint4* dp = reinterpret_cast<uint4*>(&hs[r][cseg]);
        dp[0] = o0; dp[1] = o1;
    }
    __syncthreads();

    const int wv   = __builtin_amdgcn_readfirstlane(tid >> 6);
    const int lane = tid & 63;
    const int lid  = lane & 15;
    const int quad = lane >> 4;

    // layer A: [16x64] @ [64x128] -> ts
    v8s afA0 = *reinterpret_cast<const v8s*>(&hs[wv*16 + lid][quad*8]);
    v8s afA1 = *reinterpret_cast<const v8s*>(&hs[wv*16 + lid][32 + quad*8]);
    #pragma unroll
    for (int nt = 0; nt < 8; ++nt) {
        v4f acc = {0.f, 0.f, 0.f, 0.f};
        const unsigned short* wp = W2aT + (nt*16 + lid)*64 + quad*8;
        v8s b0 = *reinterpret_cast<const v8s*>(wp);
        v8s b1 = *reinterpret_cast<const v8s*>(wp + 32);
        acc = __builtin_amdgcn_mfma_f32_16x16x32_bf16(afA0, b0, acc, 0, 0, 0);
        acc = __builtin_amdgcn_mfma_f32_16x16x32_bf16(afA1, b1, acc, 0, 0, 0);
        float bias = b2a[nt*16 + lid];
        #pragma unroll
        for (int i = 0; i < 4; ++i) {
            float v = lrelu(acc[i] + bias);
            ts[wv*16 + quad*4 + i][nt*16 + lid] = f2bf(v);
        }
    }
    __syncthreads();

    // layer B: [16x128] @ [128x256] -> h2b (bf16)
    v8s afB[4];
    #pragma unroll
    for (int ks = 0; ks < 4; ++ks)
        afB[ks] = *reinterpret_cast<const v8s*>(&ts[wv*16 + lid][ks*32 + quad*8]);
    const int gbase = n0 + wv*16 + quad*4;
    #pragma unroll 4
    for (int nt = 0; nt < 16; ++nt) {
        v4f acc = {0.f, 0.f, 0.f, 0.f};
        const unsigned short* wp = W2bT + (nt*16 + lid)*128 + quad*8;
        #pragma unroll
        for (int ks = 0; ks < 4; ++ks) {
            v8s bf = *reinterpret_cast<const v8s*>(wp + ks*32);
            acc = __builtin_amdgcn_mfma_f32_16x16x32_bf16(afB[ks], bf, acc, 0, 0, 0);
        }
        float bias = b2b[nt*16 + lid];
        #pragma unroll
        for (int i = 0; i < 4; ++i) {
            int g = gbase + i;
            if (g < N) {
                float v = lrelu(acc[i] + bias);
                h2b[(size_t)g*256 + nt*16 + lid] = f2bf(v);
            }
        }
    }
}

// ---------------- global_add_pool over sorted batch ids (bf16 h2) -------------
__global__ __launch_bounds__(256) void k_pool(
    const unsigned int* __restrict__ h2b, const int* __restrict__ batch,
    float* __restrict__ g, int N)
{
    int tid = threadIdx.x;
    int c2 = tid & 127;            // uint pair: channels 2c2, 2c2+1
    int h = tid >> 7;              // 0/1: even/odd nodes
    int base = blockIdx.x * 128;
    int n0 = base + h;
    int nend = base + 128; if (nend > N) nend = N;
    if (n0 >= N) return;
    float acc0 = 0.f, acc1 = 0.f;
    int cur = batch[n0];
    for (int n = n0; n < nend; n += 2) {
        int b = batch[n];
        unsigned int hv = h2b[(size_t)n * 128 + c2];
        if (b != cur) {
            atomicAdd(&g[(unsigned)cur * 256 + 2*c2],     acc0);
            atomicAdd(&g[(unsigned)cur * 256 + 2*c2 + 1], acc1);
            acc0 = acc1 = 0.f; cur = b;
        }
        acc0 += bflo(hv); acc1 += bfhi(hv);
    }
    atomicAdd(&g[(unsigned)cur * 256 + 2*c2],     acc0);
    atomicAdd(&g[(unsigned)cur * 256 + 2*c2 + 1], acc1);
}

// ---------------- head MLP -----------------------------------------------------
__global__ __launch_bounds__(256) void k_head(
    const float* __restrict__ g,
    const float* __restrict__ Wf0, const float* __restrict__ bf0,
    const float* __restrict__ Wf1, const float* __restrict__ bf1,
    const float* __restrict__ Wf2, const float* __restrict__ bf2,
    const float* __restrict__ Wr,  const float* __restrict__ br,
    float* __restrict__ out)
{
    __shared__ float buf[256];
    __shared__ float t0[128];
    __shared__ float t1[64];
    __shared__ float t2[32];
    int gid = blockIdx.x, tid = threadIdx.x;
    buf[tid] = g[(size_t)gid*256 + tid];
    __syncthreads();
    if (tid < 128) {
        float acc = bf0[tid];
        for (int k = 0; k < 256; ++k) acc = fmaf(buf[k], Wf0[k*128 + tid], acc);
        t0[tid] = lrelu(acc);
    }
    __syncthreads();
    if (tid < 64) {
        float acc = bf1[tid];
        for (int k = 0; k < 128; ++k) acc = fmaf(t0[k], Wf1[k*64 + tid], acc);
        t1[tid] = lrelu(acc);
    }
    __syncthreads();
    if (tid < 32) {
        float acc = bf2[tid];
        for (int k = 0; k < 64; ++k) acc = fmaf(t1[k], Wf2[k*32 + tid], acc);
        t2[tid] = lrelu(acc);
    }
    __syncthreads();
    if (tid == 0) {
        float acc = br[0];
        for (int k = 0; k < 32; ++k) acc = fmaf(t2[k], Wr[k], acc);
        out[gid] = acc;
    }
}

extern "C" void kernel_launch(void* const* d_in, const int* in_sizes, int n_in,
                              void* d_out, int out_size, void* d_ws, size_t ws_size,
                              hipStream_t stream)
{
    const float* x     = (const float*)d_in[0];
    const int*   ei    = (const int*)d_in[1];
    const float* ea    = (const float*)d_in[2];
    const int*   batch = (const int*)d_in[3];
    const float* We1=(const float*)d_in[4],  *be1=(const float*)d_in[5];
    const float* W1a=(const float*)d_in[6],  *b1a=(const float*)d_in[7];
    const float* W1b=(const float*)d_in[8],  *b1b=(const float*)d_in[9];
    const float* We2=(const float*)d_in[10], *be2=(const float*)d_in[11];
    const float* W2a=(const float*)d_in[12], *b2a=(const float*)d_in[13];
    const float* W2b=(const float*)d_in[14], *b2b=(const float*)d_in[15];
    const float* Wf0=(const float*)d_in[16], *bf0=(const float*)d_in[17];
    const float* Wf1=(const float*)d_in[18], *bf1=(const float*)d_in[19];
    const float* Wf2=(const float*)d_in[20], *bf2=(const float*)d_in[21];
    const float* Wr =(const float*)d_in[22], *br =(const float*)d_in[23];

    const int N = in_sizes[0] / 32;
    const int E = in_sizes[1] / 2;
    const int G = out_size;
    const int nb = (N + 255) / 256;
    const int nb64 = (N + 63) / 64;
    const int NBK = (N + 255) >> 8;          // buckets of 256 dst

    // ---- workspace layout ----
    // zeroed prefix: [deg N][gbuf G*256 f32][agg1 N*32 f32][agg2 N*64 f32]
    char* p = (char*)d_ws;
    int*   deg     = (int*)p;                 p += (size_t)N * 4;
    float* gbuf    = (float*)p;               p += (size_t)G * 256 * 4;
    float* agg1    = (float*)p;               p += (size_t)N * 32 * 4;
    float* agg2    = (float*)p;               p += (size_t)N * 64 * 4;
    size_t zero_bytes = (size_t)(p - (char*)d_ws);
    int*   rowptr  = (int*)p;                 p += (size_t)N * 4;
    int*   cursor  = (int*)p;                 p += (size_t)N * 4;
    int*   bsum    = (int*)p;                 p += 512 * 4;
    int*   bcur    = (int*)p;                 p += 512 * 4;
    p = (char*)(((uintptr_t)p + 63) & ~(uintptr_t)63);
    int2*  csr2    = (int2*)p;                p += (size_t)E * 8;
    uint4* eab     = (uint4*)p;               p += (size_t)E * 32;   // 16 bf16/edge
    int2*  sA      = (int2*)p;                p += (size_t)E * 8;    // staging {s,d}
    unsigned short* xb   = (unsigned short*)p; p += (size_t)N * 32 * 2;
    unsigned int*   h1b  = (unsigned int*)p;  p += (size_t)N * 64 * 2;
    unsigned short* W2aT = (unsigned short*)p; p += 128 * 64 * 2;
    unsigned short* W2bT = (unsigned short*)p; p += 256 * 128 * 2;
    unsigned short* WeT1 = (unsigned short*)p; p += 32 * 32 * 2;
    unsigned short* WeT2 = (unsigned short*)p; p += 64 * 32 * 2;
    unsigned short* h2b  = (unsigned short*)p; p += (size_t)N * 256 * 2;
    // sB (staging attrs, E*32 = 51.2MB) aliases h2b (N*256*2 = 51.2MB):
    // consumed by k_order long before k_mlp2 writes h2b.
    uint4* sB = (uint4*)h2b;

    hipMemsetAsync(d_ws, 0, zero_bytes, stream);

    int eb = (E + 255) / 256;

    // CSR build + casts
    k_hist   <<<eb, 256, 0, stream>>>(ei, deg, E);
    k_scan1  <<<nb, 256, 0, stream>>>(deg, rowptr, bsum, N);
    k_scan2  <<<1, 512, 0, stream>>>(bsum, nb);
    k_scan3  <<<nb, 256, 0, stream>>>(rowptr, cursor, bsum, N);
    k_binit  <<<1, 512, 0, stream>>>(rowptr, bcur, N);
    {
        int M8 = N * 32 / 8;
        k_castx<<<(M8 + 255) / 256, 256, 0, stream>>>(x, (unsigned int*)xb, M8);
    }
    {
        int tot = 128*64 + 256*128 + 32*32 + 64*32;
        k_castw<<<(tot + 255) / 256, 256, 0, stream>>>(W2a, W2b, We1, We2,
                                                       W2aT, W2bT, WeT1, WeT2);
    }
    // two-pass bucketed scatter
    k_bucket<<<(E + BCH - 1) / BCH, 256, 0, stream>>>(ei, ea, bcur, sA, sB, E);
    k_order <<<NBK, 256, 0, stream>>>(sA, sB, rowptr, cursor, csr2, eab, E, NBK);

    // conv1
    {
        int waves = (E + AGG_SPW - 1) / AGG_SPW;
        int blocks = (waves + 3) / 4;
        k_agg1<<<blocks, 256, 0, stream>>>(xb, eab, WeT1, be1, csr2, agg1, E);
    }
    k_mlp1<<<nb64, 256, 0, stream>>>(x, agg1, W1a, b1a, W1b, b1b,
                                     (unsigned int*)h1b, N);

    // conv2
    {
        int waves = (E + AGG_SPW - 1) / AGG_SPW;
        int blocks = (waves + 3) / 4;
        k_agg2<<<blocks, 256, 0, stream>>>((const unsigned short*)h1b, eab, WeT2,
                                           be2, csr2, agg2, E);
    }
    k_mlp2<<<nb64, 256, 0, stream>>>(h1b, agg2, W2aT, b2a, W2bT, b2b, h2b, N);

    // pool + head
    k_pool<<<(N + 127) / 128, 256, 0, stream>>>((const unsigned int*)h2b, batch,
                                                gbuf, N);
    k_head<<<G, 256, 0, stream>>>(gbuf, Wf0, bf0, Wf1, bf1, Wf2, bf2, Wr, br,
                                  (float*)d_out);
}

// Round 10
// 623.877 us; speedup vs baseline: 1.1274x; 1.1274x over previous
//
#include <hip/hip_runtime.h>

__device__ __forceinline__ float lrelu(float v){ return v > 0.f ? v : 0.01f*v; }

typedef __attribute__((ext_vector_type(8))) short v8s;   // 8 bf16 (4 VGPRs)
typedef __attribute__((ext_vector_type(4))) float v4f;   // MFMA acc

// bf16 helpers (RNE pack; unpack via shift)
__device__ __forceinline__ unsigned short f2bf(float f){
    union{float f; unsigned int i;} v; v.f = f;
    unsigned int u = v.i;
    return (unsigned short)((u + 0x7fffu + ((u >> 16) & 1u)) >> 16);
}
__device__ __forceinline__ unsigned int pack2(float a, float b){
    return (unsigned int)f2bf(a) | ((unsigned int)f2bf(b) << 16);
}
__device__ __forceinline__ float bflo(unsigned int u){
    union{unsigned int i; float f;} v; v.i = u << 16; return v.f;
}
__device__ __forceinline__ float bfhi(unsigned int u){
    union{unsigned int i; float f;} v; v.i = u & 0xffff0000u; return v.f;
}
__device__ __forceinline__ float bf2f(unsigned short s){
    union{unsigned int i; float f;} v; v.i = ((unsigned int)s) << 16; return v.f;
}

// ================= CSR build =================================================
__global__ __launch_bounds__(256) void k_hist(
    const int* __restrict__ ei, int* __restrict__ deg, int E)
{
    int e = blockIdx.x * 256 + threadIdx.x;
    if (e >= E) return;
    atomicAdd(&deg[ei[E + e]], 1);
}

__global__ __launch_bounds__(256) void k_scan1(
    const int* __restrict__ deg, int* __restrict__ rowptr,
    int* __restrict__ bsum, int N)
{
    __shared__ int sh[256];
    int t = threadIdx.x;
    int i = blockIdx.x * 256 + t;
    int v = (i < N) ? deg[i] : 0;
    sh[t] = v;
    __syncthreads();
    #pragma unroll
    for (int off = 1; off < 256; off <<= 1) {
        int add = (t >= off) ? sh[t - off] : 0;
        __syncthreads();
        sh[t] += add;
        __syncthreads();
    }
    if (i < N) rowptr[i] = sh[t] - v;
    if (t == 255) bsum[blockIdx.x] = sh[t];
}

__global__ __launch_bounds__(512) void k_scan2(int* __restrict__ bsum, int nb)
{
    __shared__ int sh[512];
    int t = threadIdx.x;
    int v = (t < nb) ? bsum[t] : 0;
    sh[t] = v;
    __syncthreads();
    #pragma unroll
    for (int off = 1; off < 512; off <<= 1) {
        int add = (t >= off) ? sh[t - off] : 0;
        __syncthreads();
        sh[t] += add;
        __syncthreads();
    }
    if (t < nb) bsum[t] = sh[t] - v;
}

__global__ __launch_bounds__(256) void k_scan3(
    int* __restrict__ rowptr, int* __restrict__ cursor,
    const int* __restrict__ bsum, int N)
{
    int i = blockIdx.x * 256 + threadIdx.x;
    if (i >= N) return;
    int rp = rowptr[i] + bsum[i >> 8];
    rowptr[i] = rp;
    cursor[i] = rp;
}

// cast x -> bf16 (8 floats / thread)
__global__ __launch_bounds__(256) void k_castx(
    const float* __restrict__ x, unsigned int* __restrict__ xb, int M8)
{
    int i = blockIdx.x * 256 + threadIdx.x;
    if (i >= M8) return;
    const float4* p = reinterpret_cast<const float4*>(x) + (size_t)i * 2;
    float4 a = p[0], b = p[1];
    uint4 o;
    o.x = pack2(a.x, a.y); o.y = pack2(a.z, a.w);
    o.z = pack2(b.x, b.y); o.w = pack2(b.z, b.w);
    reinterpret_cast<uint4*>(xb)[i] = o;
}

// one-time transpose+cast of weights to bf16 [N][K] layouts.
__global__ __launch_bounds__(256) void k_castw(
    const float* __restrict__ W2a, const float* __restrict__ W2b,
    const float* __restrict__ We1, const float* __restrict__ We2,
    unsigned short* __restrict__ W2aT, unsigned short* __restrict__ W2bT,
    unsigned short* __restrict__ WeT1, unsigned short* __restrict__ WeT2)
{
    int i = blockIdx.x * 256 + threadIdx.x;
    if (i < 128 * 64) {
        int n = i >> 6, k = i & 63;
        W2aT[i] = f2bf(W2a[k * 128 + n]);
    }
    int j = i - 128 * 64;
    if (j >= 0 && j < 256 * 128) {
        int n = j >> 7, k = j & 127;
        W2bT[j] = f2bf(W2b[k * 256 + n]);
    }
    int q1 = i - (128 * 64 + 256 * 128);
    if (q1 >= 0 && q1 < 32 * 32) {
        int cch = q1 >> 5, k = q1 & 31;
        WeT1[q1] = (k < 16) ? f2bf(We1[k * 32 + cch]) : (unsigned short)0;
    }
    int q2 = q1 - 32 * 32;
    if (q2 >= 0 && q2 < 64 * 32) {
        int cch = q2 >> 5, k = q2 & 31;
        WeT2[q2] = (k < 16) ? f2bf(We2[k * 64 + cch]) : (unsigned short)0;
    }
}

// scatter: csr2[slot]={src,dst}; eab[slot]=16 bf16 of ea row (CSR order).
// Plain one-pass scatter — measured at ~1.5x the E*64B line-touch writeback
// floor; five alternatives (idx-split, 64B records, 2x partition schemes,
// bucketed 2-pass) all measured worse. Closed.
__global__ __launch_bounds__(256) void k_scatter(
    const int* __restrict__ ei, const float* __restrict__ ea,
    int* __restrict__ cursor, int2* __restrict__ csr2,
    uint4* __restrict__ eab, int E)
{
    int e = blockIdx.x * 256 + threadIdx.x;
    if (e >= E) return;
    int s = ei[e];
    int d = ei[E + e];
    int slot = atomicAdd(&cursor[d], 1);
    const float4* p = reinterpret_cast<const float4*>(ea) + (size_t)e * 4;
    float4 a = p[0], b = p[1], c = p[2], f = p[3];
    uint4 o0, o1;
    o0.x = pack2(a.x, a.y); o0.y = pack2(a.z, a.w);
    o0.z = pack2(b.x, b.y); o0.w = pack2(b.z, b.w);
    o1.x = pack2(c.x, c.y); o1.y = pack2(c.z, c.w);
    o1.z = pack2(f.x, f.y); o1.w = pack2(f.z, f.w);
    eab[(size_t)slot * 2]     = o0;
    eab[(size_t)slot * 2 + 1] = o1;
    int2 r; r.x = s; r.y = d;
    csr2[slot] = r;
}

#define AGG_SPW 64

// ============ conv2 aggregation: MFMA edge-MLP + transposed accumulate =======
__global__ __launch_bounds__(256) void k_agg2(
    const unsigned short* __restrict__ xb,   // h1b [N][64] bf16
    const uint4* __restrict__ eab,
    const unsigned short* __restrict__ WeT,  // [64][32] bf16, K-padded
    const float* __restrict__ be,
    const int2* __restrict__ csr2, float* __restrict__ agg, int E)
{
    __shared__ __align__(16) float lds[4][2][16][68];
    const int tid  = threadIdx.x;
    const int wv   = tid >> 6;
    const int lane = tid & 63;
    const int lid  = lane & 15;
    const int quad = lane >> 4;
    const int wave = __builtin_amdgcn_readfirstlane((blockIdx.x * 256 + tid) >> 6);
    const int s0 = wave * AGG_SPW;
    if (s0 >= E) return;
    const int nsl = (s0 + AGG_SPW <= E) ? AGG_SPW : E - s0;

    v8s af0 = *reinterpret_cast<const v8s*>(WeT + lid * 32 + quad * 8);
    v8s af1 = *reinterpret_cast<const v8s*>(WeT + (16 + lid) * 32 + quad * 8);
    v8s af2 = *reinterpret_cast<const v8s*>(WeT + (32 + lid) * 32 + quad * 8);
    v8s af3 = *reinterpret_cast<const v8s*>(WeT + (48 + lid) * 32 + quad * 8);
    const float biasc = be[lane];
    const int2*  cp = csr2 + s0;
    const uint4* ep = eab + (size_t)s0 * 2;

    unsigned short xv[2][16];
    int dsv[2][16];
    float acc = 0.f;
    int   cur = cp[0].y;
    bool  owned = false;

    auto GATHER = [&](int t) {
        const int base = t * 16;
        const int cnt = nsl - base;
        #pragma unroll
        for (int e = 0; e < 16; ++e) {
            int ee = (e < cnt) ? e : cnt - 1;
            int2 r = cp[base + ee];
            dsv[t & 1][e] = r.y;
            xv[t & 1][e] = xb[(unsigned)r.x * 64u + (unsigned)lane];
        }
    };
    auto MFMA = [&](int t) {
        int sl = t * 16 + lid;
        if (sl > nsl - 1) sl = nsl - 1;
        uint4 bw = {0u, 0u, 0u, 0u};
        if (quad < 2) bw = ep[2 * sl + quad];
        union { uint4 u; v8s s; } uu; uu.u = bw;
        v8s bf = uu.s;
        v4f d0 = {0.f, 0.f, 0.f, 0.f}, d1 = d0, d2 = d0, d3 = d0;
        d0 = __builtin_amdgcn_mfma_f32_16x16x32_bf16(af0, bf, d0, 0, 0, 0);
        d1 = __builtin_amdgcn_mfma_f32_16x16x32_bf16(af1, bf, d1, 0, 0, 0);
        d2 = __builtin_amdgcn_mfma_f32_16x16x32_bf16(af2, bf, d2, 0, 0, 0);
        d3 = __builtin_amdgcn_mfma_f32_16x16x32_bf16(af3, bf, d3, 0, 0, 0);
        float* lp = &lds[wv][t & 1][lid][quad * 4];
        *reinterpret_cast<v4f*>(lp)      = d0;
        *reinterpret_cast<v4f*>(lp + 16) = d1;
        *reinterpret_cast<v4f*>(lp + 32) = d2;
        *reinterpret_cast<v4f*>(lp + 48) = d3;
    };
    auto ACCUM = [&](int t) {
        const int cnt = nsl - t * 16;
        #pragma unroll
        for (int e = 0; e < 16; ++e) {
            if (e < cnt) {
                float ls = lds[wv][t & 1][e][lane];
                float m = ls + biasc + bf2f(xv[t & 1][e]);
                m = m > 0.f ? m : 0.f;
                int d = dsv[t & 1][e];
                if (d != cur) {
                    if (owned) agg[(unsigned)cur * 64u + lane] = acc;
                    else       atomicAdd(&agg[(unsigned)cur * 64u + lane], acc);
                    acc = 0.f; cur = d; owned = true;
                }
                acc += m;
            }
        }
    };

    GATHER(0); MFMA(0);
    #pragma unroll
    for (int t = 0; t < 4; ++t) {
        if (t * 16 < nsl) {
            if ((t + 1) < 4 && (t + 1) * 16 < nsl) { GATHER(t + 1); MFMA(t + 1); }
            ACCUM(t);
        }
    }
    atomicAdd(&agg[(unsigned)cur * 64u + lane], acc);
}

// ============ conv1 aggregation: same structure, C=32, 2 edges/iter ==========
__global__ __launch_bounds__(256) void k_agg1(
    const unsigned short* __restrict__ xb,   // [N][32] bf16
    const uint4* __restrict__ eab,
    const unsigned short* __restrict__ WeT,  // [32][32] bf16, K-padded
    const float* __restrict__ be,
    const int2* __restrict__ csr2, float* __restrict__ agg, int E)
{
    __shared__ __align__(16) float lds[4][2][16][36];
    const int tid  = threadIdx.x;
    const int wv   = tid >> 6;
    const int lane = tid & 63;
    const int lid  = lane & 15;
    const int quad = lane >> 4;
    const int c    = lane & 31;
    const int sub  = lane >> 5;
    const int wave = __builtin_amdgcn_readfirstlane((blockIdx.x * 256 + tid) >> 6);
    const int s0 = wave * AGG_SPW;
    if (s0 >= E) return;
    const int nsl = (s0 + AGG_SPW <= E) ? AGG_SPW : E - s0;

    v8s af0 = *reinterpret_cast<const v8s*>(WeT + lid * 32 + quad * 8);
    v8s af1 = *reinterpret_cast<const v8s*>(WeT + (16 + lid) * 32 + quad * 8);
    const float biasc = be[c];
    const int2*  cp = csr2 + s0;
    const uint4* ep = eab + (size_t)s0 * 2;

    unsigned short xv[2][8];
    int dsv[2][8];
    float acc = 0.f;
    int cur = cp[(sub < nsl) ? sub : 0].y;

    auto GATHER = [&](int t) {
        #pragma unroll
        for (int i = 0; i < 8; ++i) {
            int e = t * 16 + 2 * i + sub;
            int ee = (e < nsl) ? e : nsl - 1;
            int2 r = cp[ee];
            dsv[t & 1][i] = r.y;
            xv[t & 1][i] = xb[(unsigned)r.x * 32u + (unsigned)c];
        }
    };
    auto MFMA = [&](int t) {
        int sl = t * 16 + lid;
        if (sl > nsl - 1) sl = nsl - 1;
        uint4 bw = {0u, 0u, 0u, 0u};
        if (quad < 2) bw = ep[2 * sl + quad];
        union { uint4 u; v8s s; } uu; uu.u = bw;
        v8s bf = uu.s;
        v4f d0 = {0.f, 0.f, 0.f, 0.f}, d1 = d0;
        d0 = __builtin_amdgcn_mfma_f32_16x16x32_bf16(af0, bf, d0, 0, 0, 0);
        d1 = __builtin_amdgcn_mfma_f32_16x16x32_bf16(af1, bf, d1, 0, 0, 0);
        float* lp = &lds[wv][t & 1][lid][quad * 4];
        *reinterpret_cast<v4f*>(lp)      = d0;
        *reinterpret_cast<v4f*>(lp + 16) = d1;
    };
    auto ACCUM = [&](int t) {
        #pragma unroll
        for (int i = 0; i < 8; ++i) {
            int e = t * 16 + 2 * i + sub;
            if (e < nsl) {
                float ls = lds[wv][t & 1][2 * i + sub][c];
                float m = ls + biasc + bf2f(xv[t & 1][i]);
                m = m > 0.f ? m : 0.f;
                int d = dsv[t & 1][i];
                if (d != cur) {
                    atomicAdd(&agg[(unsigned)cur * 32u + c], acc);
                    acc = 0.f; cur = d;
                }
                acc += m;
            }
        }
    };

    GATHER(0); MFMA(0);
    #pragma unroll
    for (int t = 0; t < 4; ++t) {
        if (t * 16 < nsl) {
            if ((t + 1) < 4 && (t + 1) * 16 < nsl) { GATHER(t + 1); MFMA(t + 1); }
            ACCUM(t);
        }
    }
    atomicAdd(&agg[(unsigned)cur * 32u + c], acc);
}

// ============ conv1 node nn, fused; writes h1b bf16 only =====================
__global__ __launch_bounds__(256, 4) void k_mlp1(
    const float* __restrict__ x, const float* __restrict__ agg1,
    const float* __restrict__ W1a, const float* __restrict__ b1a,
    const float* __restrict__ W1b, const float* __restrict__ b1b,
    unsigned int* __restrict__ h1b, int N)
{
    __shared__ float ts[64][33];
    const int tid = threadIdx.x;
    const int n0 = blockIdx.x * 64;
    const int row = tid & 63;
    const int grp = __builtin_amdgcn_readfirstlane(tid >> 6);
    const int g = n0 + row;

    float hv[32];
    if (g < N) {
        const float4* xp = reinterpret_cast<const float4*>(x) + (size_t)g * 8;
        const float4* ap = reinterpret_cast<const float4*>(agg1) + (size_t)g * 8;
        #pragma unroll
        for (int q = 0; q < 8; ++q) {
            float4 a = xp[q], b = ap[q];
            hv[4*q+0]=a.x+b.x; hv[4*q+1]=a.y+b.y;
            hv[4*q+2]=a.z+b.z; hv[4*q+3]=a.w+b.w;
        }
    } else {
        #pragma unroll
        for (int q = 0; q < 32; ++q) hv[q] = 0.f;
    }

    {
        const int c0 = grp * 8;
        float acc[8];
        #pragma unroll
        for (int i = 0; i < 8; ++i) acc[i] = b1a[c0 + i];
        for (int k = 0; k < 32; ++k) {
            float h = hv[k];
            const float* w = W1a + k*32 + c0;
            #pragma unroll
            for (int i = 0; i < 8; ++i) acc[i] = fmaf(h, w[i], acc[i]);
        }
        #pragma unroll
        for (int i = 0; i < 8; ++i) ts[row][c0 + i] = lrelu(acc[i]);
    }
    __syncthreads();

    {
        const int c0 = grp * 16;
        float acc[16];
        #pragma unroll
        for (int i = 0; i < 16; ++i) acc[i] = b1b[c0 + i];
        for (int k = 0; k < 32; ++k) {
            float tv = ts[row][k];
            const float* w = W1b + k*64 + c0;
            #pragma unroll
            for (int i = 0; i < 16; ++i) acc[i] = fmaf(tv, w[i], acc[i]);
        }
        if (g < N) {
            #pragma unroll
            for (int i = 0; i < 16; ++i) acc[i] = lrelu(acc[i]);
            uint4 p0, p1;
            p0.x = pack2(acc[0],  acc[1]);  p0.y = pack2(acc[2],  acc[3]);
            p0.z = pack2(acc[4],  acc[5]);  p0.w = pack2(acc[6],  acc[7]);
            p1.x = pack2(acc[8],  acc[9]);  p1.y = pack2(acc[10], acc[11]);
            p1.z = pack2(acc[12], acc[13]); p1.w = pack2(acc[14], acc[15]);
            uint4* bp = reinterpret_cast<uint4*>(h1b + (size_t)g*32 + (c0>>1));
            bp[0] = p0; bp[1] = p1;
        }
    }
}

// ============ conv2 node nn via MFMA bf16 (stages from h1b bf16) =============
__global__ __launch_bounds__(256) void k_mlp2(
    const unsigned int* __restrict__ h1b, const float* __restrict__ agg2,
    const unsigned short* __restrict__ W2aT, const float* __restrict__ b2a,
    const unsigned short* __restrict__ W2bT, const float* __restrict__ b2b,
    unsigned short* __restrict__ h2b, int N)
{
    __shared__ unsigned short hs[64][72];    // 64 x 64 bf16 (+pad)
    __shared__ unsigned short ts[64][136];   // 64 x 128 bf16 (+pad)
    const int tid = threadIdx.x;
    const int n0 = blockIdx.x * 64;

    // stage hs = bf16(h1 + agg2)
    {
        int r = tid >> 2, cseg = (tid & 3) * 16;
        int g = n0 + r;
        uint4 o0 = {0,0,0,0}, o1 = {0,0,0,0};
        if (g < N) {
            const uint4* hp = reinterpret_cast<const uint4*>(
                                  h1b + (size_t)g*32 + (cseg>>1));
            const float4* ap = reinterpret_cast<const float4*>(agg2)
                               + (size_t)g*16 + (cseg>>2);
            uint4 u0 = hp[0], u1 = hp[1];
            float4 b0=ap[0], b1=ap[1], b2=ap[2], b3=ap[3];
            o0.x = pack2(bflo(u0.x)+b0.x, bfhi(u0.x)+b0.y);
            o0.y = pack2(bflo(u0.y)+b0.z, bfhi(u0.y)+b0.w);
            o0.z = pack2(bflo(u0.z)+b1.x, bfhi(u0.z)+b1.y);
            o0.w = pack2(bflo(u0.w)+b1.z, bfhi(u0.w)+b1.w);
            o1.x = pack2(bflo(u1.x)+b2.x, bfhi(u1.x)+b2.y);
            o1.y = pack2(bflo(u1.y)+b2.z, bfhi(u1.y)+b2.w);
            o1.z = pack2(bflo(u1.z)+b3.x, bfhi(u1.z)+b3.y);
            o1.w = pack2(bflo(u1.w)+b3.z, bfhi(u1.w)+b3.w);
        }
        uint4* dp = reinterpret_cast<uint4*>(&hs[r][cseg]);
        dp[0] = o0; dp[1] = o1;
    }
    __syncthreads();

    const int wv   = __builtin_amdgcn_readfirstlane(tid >> 6);
    const int lane = tid & 63;
    const int lid  = lane & 15;
    const int quad = lane >> 4;

    // layer A: [16x64] @ [64x128] -> ts
    v8s afA0 = *reinterpret_cast<const v8s*>(&hs[wv*16 + lid][quad*8]);
    v8s afA1 = *reinterpret_cast<const v8s*>(&hs[wv*16 + lid][32 + quad*8]);
    #pragma unroll
    for (int nt = 0; nt < 8; ++nt) {
        v4f acc = {0.f, 0.f, 0.f, 0.f};
        const unsigned short* wp = W2aT + (nt*16 + lid)*64 + quad*8;
        v8s b0 = *reinterpret_cast<const v8s*>(wp);
        v8s b1 = *reinterpret_cast<const v8s*>(wp + 32);
        acc = __builtin_amdgcn_mfma_f32_16x16x32_bf16(afA0, b0, acc, 0, 0, 0);
        acc = __builtin_amdgcn_mfma_f32_16x16x32_bf16(afA1, b1, acc, 0, 0, 0);
        float bias = b2a[nt*16 + lid];
        #pragma unroll
        for (int i = 0; i < 4; ++i) {
            float v = lrelu(acc[i] + bias);
            ts[wv*16 + quad*4 + i][nt*16 + lid] = f2bf(v);
        }
    }
    __syncthreads();

    // layer B: [16x128] @ [128x256] -> h2b (bf16)
    v8s afB[4];
    #pragma unroll
    for (int ks = 0; ks < 4; ++ks)
        afB[ks] = *reinterpret_cast<const v8s*>(&ts[wv*16 + lid][ks*32 + quad*8]);
    const int gbase = n0 + wv*16 + quad*4;
    #pragma unroll 4
    for (int nt = 0; nt < 16; ++nt) {
        v4f acc = {0.f, 0.f, 0.f, 0.f};
        const unsigned short* wp = W2bT + (nt*16 + lid)*128 + quad*8;
        #pragma unroll
        for (int ks = 0; ks < 4; ++ks) {
            v8s bf = *reinterpret_cast<const v8s*>(wp + ks*32);
            acc = __builtin_amdgcn_mfma_f32_16x16x32_bf16(afB[ks], bf, acc, 0, 0, 0);
        }
        float bias = b2b[nt*16 + lid];
        #pragma unroll
        for (int i = 0; i < 4; ++i) {
            int g = gbase + i;
            if (g < N) {
                float v = lrelu(acc[i] + bias);
                h2b[(size_t)g*256 + nt*16 + lid] = f2bf(v);
            }
        }
    }
}

// ---------------- global_add_pool over sorted batch ids (bf16 h2) -------------
__global__ __launch_bounds__(256) void k_pool(
    const unsigned int* __restrict__ h2b, const int* __restrict__ batch,
    float* __restrict__ g, int N)
{
    int tid = threadIdx.x;
    int c2 = tid & 127;            // uint pair: channels 2c2, 2c2+1
    int h = tid >> 7;              // 0/1: even/odd nodes
    int base = blockIdx.x * 128;
    int n0 = base + h;
    int nend = base + 128; if (nend > N) nend = N;
    if (n0 >= N) return;
    float acc0 = 0.f, acc1 = 0.f;
    int cur = batch[n0];
    for (int n = n0; n < nend; n += 2) {
        int b = batch[n];
        unsigned int hv = h2b[(size_t)n * 128 + c2];
        if (b != cur) {
            atomicAdd(&g[(unsigned)cur * 256 + 2*c2],     acc0);
            atomicAdd(&g[(unsigned)cur * 256 + 2*c2 + 1], acc1);
            acc0 = acc1 = 0.f; cur = b;
        }
        acc0 += bflo(hv); acc1 += bfhi(hv);
    }
    atomicAdd(&g[(unsigned)cur * 256 + 2*c2],     acc0);
    atomicAdd(&g[(unsigned)cur * 256 + 2*c2 + 1], acc1);
}

// ---------------- head MLP -----------------------------------------------------
__global__ __launch_bounds__(256) void k_head(
    const float* __restrict__ g,
    const float* __restrict__ Wf0, const float* __restrict__ bf0,
    const float* __restrict__ Wf1, const float* __restrict__ bf1,
    const float* __restrict__ Wf2, const float* __restrict__ bf2,
    const float* __restrict__ Wr,  const float* __restrict__ br,
    float* __restrict__ out)
{
    __shared__ float buf[256];
    __shared__ float t0[128];
    __shared__ float t1[64];
    __shared__ float t2[32];
    int gid = blockIdx.x, tid = threadIdx.x;
    buf[tid] = g[(size_t)gid*256 + tid];
    __syncthreads();
    if (tid < 128) {
        float acc = bf0[tid];
        for (int k = 0; k < 256; ++k) acc = fmaf(buf[k], Wf0[k*128 + tid], acc);
        t0[tid] = lrelu(acc);
    }
    __syncthreads();
    if (tid < 64) {
        float acc = bf1[tid];
        for (int k = 0; k < 128; ++k) acc = fmaf(t0[k], Wf1[k*64 + tid], acc);
        t1[tid] = lrelu(acc);
    }
    __syncthreads();
    if (tid < 32) {
        float acc = bf2[tid];
        for (int k = 0; k < 64; ++k) acc = fmaf(t1[k], Wf2[k*32 + tid], acc);
        t2[tid] = lrelu(acc);
    }
    __syncthreads();
    if (tid == 0) {
        float acc = br[0];
        for (int k = 0; k < 32; ++k) acc = fmaf(t2[k], Wr[k], acc);
        out[gid] = acc;
    }
}

extern "C" void kernel_launch(void* const* d_in, const int* in_sizes, int n_in,
                              void* d_out, int out_size, void* d_ws, size_t ws_size,
                              hipStream_t stream)
{
    const float* x     = (const float*)d_in[0];
    const int*   ei    = (const int*)d_in[1];
    const float* ea    = (const float*)d_in[2];
    const int*   batch = (const int*)d_in[3];
    const float* We1=(const float*)d_in[4],  *be1=(const float*)d_in[5];
    const float* W1a=(const float*)d_in[6],  *b1a=(const float*)d_in[7];
    const float* W1b=(const float*)d_in[8],  *b1b=(const float*)d_in[9];
    const float* We2=(const float*)d_in[10], *be2=(const float*)d_in[11];
    const float* W2a=(const float*)d_in[12], *b2a=(const float*)d_in[13];
    const float* W2b=(const float*)d_in[14], *b2b=(const float*)d_in[15];
    const float* Wf0=(const float*)d_in[16], *bf0=(const float*)d_in[17];
    const float* Wf1=(const float*)d_in[18], *bf1=(const float*)d_in[19];
    const float* Wf2=(const float*)d_in[20], *bf2=(const float*)d_in[21];
    const float* Wr =(const float*)d_in[22], *br =(const float*)d_in[23];

    const int N = in_sizes[0] / 32;
    const int E = in_sizes[1] / 2;
    const int G = out_size;
    const int nb = (N + 255) / 256;
    const int nb64 = (N + 63) / 64;

    // ---- workspace layout ----
    // zeroed prefix: [deg N][gbuf G*256 f32][agg1 N*32 f32][agg2 N*64 f32]
    char* p = (char*)d_ws;
    int*   deg     = (int*)p;                 p += (size_t)N * 4;
    float* gbuf    = (float*)p;               p += (size_t)G * 256 * 4;
    float* agg1    = (float*)p;               p += (size_t)N * 32 * 4;
    float* agg2    = (float*)p;               p += (size_t)N * 64 * 4;
    size_t zero_bytes = (size_t)(p - (char*)d_ws);
    int*   rowptr  = (int*)p;                 p += (size_t)N * 4;
    int*   cursor  = (int*)p;                 p += (size_t)N * 4;
    int*   bsum    = (int*)p;                 p += 512 * 4;
    p = (char*)(((uintptr_t)p + 63) & ~(uintptr_t)63);
    int2*  csr2    = (int2*)p;                p += (size_t)E * 8;
    uint4* eab     = (uint4*)p;               p += (size_t)E * 32;   // 16 bf16/edge
    unsigned short* xb   = (unsigned short*)p; p += (size_t)N * 32 * 2;
    unsigned int*   h1b  = (unsigned int*)p;  p += (size_t)N * 64 * 2;
    unsigned short* W2aT = (unsigned short*)p; p += 128 * 64 * 2;
    unsigned short* W2bT = (unsigned short*)p; p += 256 * 128 * 2;
    unsigned short* WeT1 = (unsigned short*)p; p += 32 * 32 * 2;
    unsigned short* WeT2 = (unsigned short*)p; p += 64 * 32 * 2;
    unsigned short* h2b  = (unsigned short*)p; p += (size_t)N * 256 * 2;

    hipMemsetAsync(d_ws, 0, zero_bytes, stream);

    int eb = (E + 255) / 256;

    // CSR build + casts
    k_hist   <<<eb, 256, 0, stream>>>(ei, deg, E);
    k_scan1  <<<nb, 256, 0, stream>>>(deg, rowptr, bsum, N);
    k_scan2  <<<1, 512, 0, stream>>>(bsum, nb);
    k_scan3  <<<nb, 256, 0, stream>>>(rowptr, cursor, bsum, N);
    {
        int M8 = N * 32 / 8;
        k_castx<<<(M8 + 255) / 256, 256, 0, stream>>>(x, (unsigned int*)xb, M8);
    }
    {
        int tot = 128*64 + 256*128 + 32*32 + 64*32;
        k_castw<<<(tot + 255) / 256, 256, 0, stream>>>(W2a, W2b, We1, We2,
                                                       W2aT, W2bT, WeT1, WeT2);
    }
    k_scatter<<<eb, 256, 0, stream>>>(ei, ea, cursor, csr2, eab, E);

    // conv1
    {
        int waves = (E + AGG_SPW - 1) / AGG_SPW;
        int blocks = (waves + 3) / 4;
        k_agg1<<<blocks, 256, 0, stream>>>(xb, eab, WeT1, be1, csr2, agg1, E);
    }
    k_mlp1<<<nb64, 256, 0, stream>>>(x, agg1, W1a, b1a, W1b, b1b,
                                     (unsigned int*)h1b, N);

    // conv2
    {
        int waves = (E + AGG_SPW - 1) / AGG_SPW;
        int blocks = (waves + 3) / 4;
        k_agg2<<<blocks, 256, 0, stream>>>((const unsigned short*)h1b, eab, WeT2,
                                           be2, csr2, agg2, E);
    }
    k_mlp2<<<nb64, 256, 0, stream>>>(h1b, agg2, W2aT, b2a, W2bT, b2b, h2b, N);

    // pool + head
    k_pool<<<(N + 127) / 128, 256, 0, stream>>>((const unsigned int*)h2b, batch,
                                                gbuf, N);
    k_head<<<G, 256, 0, stream>>>(gbuf, Wf0, bf0, Wf1, bf1, Wf2, bf2, Wr, br,
                                  (float*)d_out);
}